// Round 19
// baseline (248.157 us; speedup 1.0000x reference)
//
#include <hip/hip_runtime.h>
#include <hip/hip_bf16.h>

#define N_ROWS 100000
#define P_DIM 512
#define D_DIM 256
#define TAU12 2.0e-2f
#define TAU13 1.5e-2f

typedef __attribute__((ext_vector_type(4))) float f32x4;
typedef __attribute__((ext_vector_type(8))) short s16x8;

__device__ __forceinline__ unsigned bf16_rne_bits(float x) {
  unsigned u = __float_as_uint(x);
  return (u + 0x7fffu + ((u >> 16) & 1u)) >> 16;
}

__device__ __forceinline__ void gll16(const void* gsrc, void* ldst) {
  __builtin_amdgcn_global_load_lds(
      (const __attribute__((address_space(1))) unsigned char*)gsrc,
      (__attribute__((address_space(3))) unsigned char*)ldst, 16, 0, 0);
}

union BP2 { __hip_bfloat162 h; unsigned u; };
union BP8 { unsigned u[4]; s16x8 v; };

// ---------------- prep + out_hot zeroing (unchanged from r18) ----------------
#define ZERO_BLOCKS 3328
__global__ void prep_kernel(const float* __restrict__ patch,
                            short* __restrict__ pa_swz,
                            short* __restrict__ p_T_perm,
                            float* __restrict__ out_hot) {
  int b = blockIdx.x, t = threadIdx.x;
  if (b >= 128) {
    const int nunits = (N_ROWS * P_DIM) / 4;
    f32x4* dst = (f32x4*)out_hot;
    const f32x4 z = (f32x4){0.f, 0.f, 0.f, 0.f};
    int stride = ZERO_BLOCKS * 256;
#pragma unroll 1
    for (int u = (b - 128) * 256 + t; u < nunits; u += stride)
      __builtin_nontemporal_store(z, dst + u);
    return;
  }
  if (b < 64) {
    int u = b * 256 + t;
    int bt = u >> 11;
    int Lb = (u & 2047) * 16;
    int r  = Lb >> 9;
    int srcb = Lb ^ ((r & 15) << 4);
    int p = bt * 64 + r;
    int d0 = (srcb & 511) >> 1;
    s16x8 v;
#pragma unroll
    for (int q = 0; q < 8; ++q)
      v[q] = (short)bf16_rne_bits(patch[(size_t)p * D_DIM + d0 + q]);
    *(s16x8*)(pa_swz + (size_t)u * 8) = v;
  } else {
    int u = (b - 64) * 256 + t;
    int g = u & 3, cc = (u >> 2) & 15, kc = (u >> 6) & 15, t2 = u >> 10;
    int d = t2 * 16 + cc;
    s16x8 v;
#pragma unroll
    for (int j = 0; j < 8; ++j) {
      int p = 32 * kc + 16 * (j >> 2) + 4 * g + (j & 3);
      v[j] = (short)bf16_rne_bits(patch[(size_t)p * D_DIM + d]);
    }
    *(s16x8*)(p_T_perm + (size_t)u * 8) = v;
  }
}

#define STAGE_PA(BUF, T) do {                                         \
  const char* gs_ = (const char*)pa_swz + (size_t)(T) * 16384         \
                    + (size_t)w * 4096 + (size_t)lane * 16;           \
  char* ls_ = SH + (BUF) * 16384 + w * 4096;                          \
  _Pragma("unroll")                                                   \
  for (int i_ = 0; i_ < 4; ++i_)                                      \
    gll16(gs_ + i_ * 1024, ls_ + i_ * 1024);                          \
} while (0)

// ---------------- gemm1: logits + softmax-pack + argmax + refine -----------
// (256,4): no C2/aW/BT -> live ~100 regs -> 16 waves/CU. LDS = pa 2x16KB.
// Streams unnormalized bf16 probs (pf) into the out_rec region per tile.
__global__ __launch_bounds__(256, 4)
void gemm1_kernel(const float* __restrict__ node,
                  const float* __restrict__ patch,
                  const short* __restrict__ pa_swz,
                  short* __restrict__ pfout,         // = out_rec region
                  float* __restrict__ out_hot,
                  float* __restrict__ invs) {
  __shared__ __align__(16) char SH[32768];

  const int tid = threadIdx.x;
  const int lane = tid & 63;
  const int w = tid >> 6;
  const int cc = lane & 15, g = lane >> 4;
  const int G = blockIdx.x * 4 + w;
  const int myrow = G * 16 + cc;
  const bool ok = (G * 16) < N_ROWS;

  STAGE_PA(0, 0);

  s16x8 nhi[8];
  {
    const float* nr = node + (size_t)myrow * D_DIM;
#pragma unroll
    for (int kk = 0; kk < 8; ++kk) {
      f32x4 v0, v1;
      if (ok) {
        v0 = __builtin_nontemporal_load((const f32x4*)(nr + kk * 32 + g * 8));
        v1 = __builtin_nontemporal_load((const f32x4*)(nr + kk * 32 + g * 8 + 4));
      } else {
        v0 = (f32x4){0.f, 0.f, 0.f, 0.f};
        v1 = (f32x4){0.f, 0.f, 0.f, 0.f};
      }
      BP2 w0, w1, w2, w3;
      w0.h = __float22bfloat162_rn(make_float2(v0[0], v0[1]));
      w1.h = __float22bfloat162_rn(make_float2(v0[2], v0[3]));
      w2.h = __float22bfloat162_rn(make_float2(v1[0], v1[1]));
      w3.h = __float22bfloat162_rn(make_float2(v1[2], v1[3]));
      BP8 nv;
      nv.u[0] = w0.u; nv.u[1] = w1.u; nv.u[2] = w2.u; nv.u[3] = w3.u;
      nhi[kk] = nv.v;
    }
  }
  __syncthreads();

  float m1 = -1e30f, m2 = -1e30f, m3 = -1e30f;
  int i1 = 0, i2 = 0;
  float s = 0.f;

  auto upd = [&](float v, int col) {
    bool g1 = v > m1, g2 = v > m2, g3 = v > m3;
    m3 = g2 ? m2 : (g3 ? v : m3);
    i2 = g1 ? i1 : (g2 ? col : i2);
    m2 = g1 ? m1 : (g2 ? v : m2);
    i1 = g1 ? col : i1;
    m1 = g1 ? v : m1;
  };

#pragma unroll 1
  for (int t = 0; t < 16; ++t) {
    if (t < 15) STAGE_PA((t + 1) & 1, t + 1);
    const char* bp = SH + (t & 1) * 16384;
    f32x4 a0e = (f32x4){0.f, 0.f, 0.f, 0.f};
    f32x4 a0o = (f32x4){0.f, 0.f, 0.f, 0.f};
    f32x4 a1e = (f32x4){0.f, 0.f, 0.f, 0.f};
    f32x4 a1o = (f32x4){0.f, 0.f, 0.f, 0.f};
    __builtin_amdgcn_s_setprio(1);
#pragma unroll
    for (int kk = 0; kk < 8; kk += 2) {
      int sw0 = ((kk << 6) | (g << 4)) ^ (cc << 4);
      int sw1 = (((kk + 1) << 6) | (g << 4)) ^ (cc << 4);
      s16x8 af00 = *(const s16x8*)(bp + (cc << 9) + sw0);
      s16x8 af10 = *(const s16x8*)(bp + ((16 + cc) << 9) + sw0);
      s16x8 af01 = *(const s16x8*)(bp + (cc << 9) + sw1);
      s16x8 af11 = *(const s16x8*)(bp + ((16 + cc) << 9) + sw1);
      a0e = __builtin_amdgcn_mfma_f32_16x16x32_bf16(af00, nhi[kk], a0e, 0, 0, 0);
      a1e = __builtin_amdgcn_mfma_f32_16x16x32_bf16(af10, nhi[kk], a1e, 0, 0, 0);
      a0o = __builtin_amdgcn_mfma_f32_16x16x32_bf16(af01, nhi[kk + 1], a0o, 0, 0, 0);
      a1o = __builtin_amdgcn_mfma_f32_16x16x32_bf16(af11, nhi[kk + 1], a1o, 0, 0, 0);
    }
    __builtin_amdgcn_s_setprio(0);
    f32x4 pA0 = a0e + a0o;
    f32x4 pA1 = a1e + a1o;
    // inline finalize: exp + sum + top3 + pack + pf store
    {
      float e0 = __expf(pA0[0]), e1 = __expf(pA0[1]);
      float e2 = __expf(pA0[2]), e3 = __expf(pA0[3]);
      float e4 = __expf(pA1[0]), e5 = __expf(pA1[1]);
      float e6 = __expf(pA1[2]), e7 = __expf(pA1[3]);
      s += ((e0 + e1) + (e2 + e3)) + ((e4 + e5) + (e6 + e7));
      int colb = 32 * t + 4 * g;
      upd(pA0[0], colb + 0);  upd(pA0[1], colb + 1);
      upd(pA0[2], colb + 2);  upd(pA0[3], colb + 3);
      upd(pA1[0], colb + 16); upd(pA1[1], colb + 17);
      upd(pA1[2], colb + 18); upd(pA1[3], colb + 19);
      BP2 u0, u1, u2, u3;
      u0.h = __float22bfloat162_rn(make_float2(e0, e1));
      u1.h = __float22bfloat162_rn(make_float2(e2, e3));
      u2.h = __float22bfloat162_rn(make_float2(e4, e5));
      u3.h = __float22bfloat162_rn(make_float2(e6, e7));
      BP8 pv;
      pv.u[0] = u0.u; pv.u[1] = u1.u; pv.u[2] = u2.u; pv.u[3] = u3.u;
      if (ok)
        *(s16x8*)(pfout + ((size_t)G * 1024 + t * 64 + lane) * 8) = pv.v;
    }
    __syncthreads();
  }

  // ---- merge top-3 across the 4 g-lanes of each row ----
#pragma unroll
  for (int mk = 16; mk <= 32; mk <<= 1) {
    float bm1 = __shfl_xor(m1, mk); int bi1 = __shfl_xor(i1, mk);
    float bm2 = __shfl_xor(m2, mk); int bi2 = __shfl_xor(i2, mk);
    float bm3 = __shfl_xor(m3, mk);
    bool sw = (bm1 > m1) || (bm1 == m1 && bi1 < i1);
    float am1 = sw ? bm1 : m1; int ai1 = sw ? bi1 : i1;
    float am2 = sw ? bm2 : m2; int ai2 = sw ? bi2 : i2;
    float am3 = sw ? bm3 : m3;
    float cm1 = sw ? m1 : bm1; int ci1 = sw ? i1 : bi1;
    float cm2 = sw ? m2 : bm2;
    bool t2b = (cm1 > am2) || (cm1 == am2 && ci1 < ai2);
    m1 = am1; i1 = ai1;
    m2 = t2b ? cm1 : am2; i2 = t2b ? ci1 : ai2;
    m3 = t2b ? fmaxf(am2, cm2) : fmaxf(am3, cm1);
  }
  s += __shfl_xor(s, 16);
  s += __shfl_xor(s, 32);

  if (g == 0 && ok) invs[myrow] = 1.0f / s;

  const bool flag12 = (m1 - m2 < TAU12);
  if (ok && g == 0 && !flag12)
    __builtin_nontemporal_store(1.0f, out_hot + (size_t)myrow * P_DIM + i1);

  // ---- in-wave refine: fp64 check of candidates for suspect rows ----
  unsigned long long smask = __ballot(ok && g == 0 && flag12);
  if (smask) {
    unsigned long long fmask = __ballot(ok && g == 0 && (m1 - m3 < TAU13));
#pragma unroll 1
    while (smask) {
      int src = __ffsll((long long)smask) - 1;
      smask &= smask - 1;
      int row = G * 16 + src;
      int ci1 = __shfl(i1, src);
      int ci2 = __shfl(i2, src);
      if (!((fmask >> src) & 1ull)) {
        int pidx = (lane >= 32) ? ci2 : ci1;
        int l5 = lane & 31;
        double sd = 0.0;
#pragma unroll
        for (int q = 0; q < 8; ++q) {
          int d = l5 * 8 + q;
          sd += (double)node[(size_t)row * D_DIM + d] *
                (double)patch[(size_t)pidx * D_DIM + d];
        }
#pragma unroll
        for (int mk = 1; mk <= 16; mk <<= 1) sd += __shfl_xor(sd, mk);
        double d1 = __shfl(sd, 0), d2 = __shfl(sd, 32);
        int win = (d2 > d1) ? ci2 : ((d2 == d1) ? (ci1 < ci2 ? ci1 : ci2) : ci1);
        if (lane == 0)
          out_hot[(size_t)row * P_DIM + win] = 1.0f;
      } else {
        double bv = -1e300;
        int bi = 0;
#pragma unroll 1
        for (int pp = 0; pp < 8; ++pp) {
          int p = pp * 64 + lane;
          double sd = 0.0;
          for (int d = 0; d < D_DIM; d += 4) {
            float4 f = *(const float4*)(patch + (size_t)p * D_DIM + d);
            sd += (double)node[(size_t)row * D_DIM + d]     * (double)f.x
                + (double)node[(size_t)row * D_DIM + d + 1] * (double)f.y
                + (double)node[(size_t)row * D_DIM + d + 2] * (double)f.z
                + (double)node[(size_t)row * D_DIM + d + 3] * (double)f.w;
          }
          if (sd > bv) { bv = sd; bi = p; }
        }
#pragma unroll
        for (int mk = 1; mk < 64; mk <<= 1) {
          double ov = __shfl_xor(bv, mk);
          int oi = __shfl_xor(bi, mk);
          if (ov > bv || (ov == bv && oi < bi)) { bv = ov; bi = oi; }
        }
        if (lane == 0)
          out_hot[(size_t)row * P_DIM + bi] = 1.0f;
      }
    }
  }
}

// ---------------- gemm2: rec = (pf @ patch) * inv ---------------------------
// (256,2), pf fully in regs (compile-time indexed), pT via BT LDS staging,
// transposed coalesced rec epilogue. Reads its own group's pf from the rec
// region then overwrites it (race-free: one block owns the 4 groups).
#define STAGE_PT(BUF, T) do {                                         \
  const char* gs_ = (const char*)p_T_perm + ((size_t)(T) << 10)       \
                    + ((size_t)lane << 4);                            \
  _Pragma("unroll")                                                   \
  for (int i_ = 0; i_ < 4; ++i_) {                                    \
    int t2_ = i_ * 4 + w;                                             \
    gll16(gs_ + ((size_t)t2_ << 14),                                  \
          SH + (BUF) * 16384 + (t2_ << 10) + (lane << 4));            \
  }                                                                   \
} while (0)

#define G2_TILE(T, PF) do {                                                    \
  if ((T) < 15) STAGE_PT(((T) + 1) & 1, (T) + 1);                              \
  const char* btp_ = SH + ((T) & 1) * 16384;                                   \
  s16x8 aW[16];                                                                \
  _Pragma("unroll")                                                            \
  for (int q_ = 0; q_ < 16; ++q_)                                              \
    aW[q_] = *(const s16x8*)(btp_ + (q_ << 10) + (lidx << 4));                 \
  __builtin_amdgcn_s_setprio(1);                                               \
  _Pragma("unroll")                                                            \
  for (int q_ = 0; q_ < 16; ++q_)                                              \
    C2[q_] = __builtin_amdgcn_mfma_f32_16x16x32_bf16(aW[q_], PF, C2[q_], 0, 0, 0); \
  __builtin_amdgcn_s_setprio(0);                                               \
  __syncthreads();                                                             \
} while (0)

__global__ __launch_bounds__(256, 2)
void gemm2_kernel(const short* __restrict__ p_T_perm,
                  const float* __restrict__ invs,
                  float* __restrict__ rec) {
  __shared__ __align__(16) char SH[65536];   // BT 2x16KB; whole reused at end

  const int tid = threadIdx.x;
  const int lane = tid & 63;
  const int w = tid >> 6;
  const int cc = lane & 15, g = lane >> 4;
  const int G = blockIdx.x * 4 + w;
  const int myrow = G * 16 + cc;
  const bool ok = (G * 16) < N_ROWS;
  const int lidx = (cc << 2) + g;

  STAGE_PT(0, 0);

  const s16x8* pf8 = (const s16x8*)rec;
  s16x8 pfA[8], pfB[8];
#pragma unroll
  for (int kc = 0; kc < 8; ++kc) {
    if (ok) {
      pfA[kc] = pf8[(size_t)G * 1024 + kc * 64 + lane];
      pfB[kc] = pf8[(size_t)G * 1024 + 512 + kc * 64 + lane];
    } else {
      pfA[kc] = (s16x8){0,0,0,0,0,0,0,0};
      pfB[kc] = (s16x8){0,0,0,0,0,0,0,0};
    }
  }
  const float inv = ok ? invs[myrow] : 0.f;

  f32x4 C2[16];
#pragma unroll
  for (int q = 0; q < 16; ++q) C2[q] = (f32x4){0.f, 0.f, 0.f, 0.f};
  __syncthreads();                         // BT tile 0 staged

#pragma unroll
  for (int t = 0; t < 8; ++t)  G2_TILE(t, pfA[t]);
#pragma unroll
  for (int t = 8; t < 16; ++t) G2_TILE(t, pfB[t - 8]);

  // ---- transposed rec store: C2*inv -> LDS scratch -> coalesced rows ----
  {
    float* scr = (float*)(SH + w * 16384);
#pragma unroll
    for (int t2 = 0; t2 < 16; ++t2) {
      int colb = 16 * t2 + 4 * g;
      f32x4 c2 = C2[t2];
      c2[0] *= inv; c2[1] *= inv; c2[2] *= inv; c2[3] *= inv;
      *(f32x4*)&scr[cc * 256 + (colb ^ ((cc & 3) << 4))] = c2;
    }
  }
  asm volatile("s_waitcnt lgkmcnt(0)" ::: "memory");
  __builtin_amdgcn_sched_barrier(0);
  if (ok) {
    const float* scr = (const float*)(SH + w * 16384);
#pragma unroll 1
    for (int rr = 0; rr < 16; ++rr) {
      f32x4 v = *(const f32x4*)&scr[rr * 256 + ((lane * 4) ^ ((rr & 3) << 4))];
      __builtin_nontemporal_store(
          v, (f32x4*)(rec + (size_t)(G * 16 + rr) * D_DIM + lane * 4));
    }
  }
}

extern "C" void kernel_launch(void* const* d_in, const int* in_sizes, int n_in,
                              void* d_out, int out_size, void* d_ws, size_t ws_size,
                              hipStream_t stream) {
  const float* node  = (const float*)d_in[0];
  const float* patch = (const float*)d_in[1];
  float* out_hot = (float*)d_out;
  float* out_rec = out_hot + (size_t)N_ROWS * P_DIM;

  char* ws = (char*)d_ws;
  short* pa_swz   = (short*)ws;                                   // 256 KB
  short* p_T_perm = pa_swz + 131072;                              // 256 KB
  float* invs     = (float*)(ws + 524288);                        // 400 KB

  prep_kernel<<<128 + ZERO_BLOCKS, 256, 0, stream>>>(patch, pa_swz, p_T_perm,
                                                     out_hot);
  gemm1_kernel<<<(N_ROWS + 63) / 64, 256, 0, stream>>>(node, patch, pa_swz,
                                                       (short*)out_rec, out_hot,
                                                       invs);
  gemm2_kernel<<<(N_ROWS + 63) / 64, 256, 0, stream>>>(p_T_perm, invs, out_rec);
}

// Round 20
// 236.530 us; speedup vs baseline: 1.0492x; 1.0492x over previous
//
#include <hip/hip_runtime.h>
#include <hip/hip_bf16.h>

#define N_ROWS 100000
#define P_DIM 512
#define D_DIM 256
#define TAU12 2.0e-2f
#define TAU13 1.5e-2f

typedef __attribute__((ext_vector_type(4))) float f32x4;
typedef __attribute__((ext_vector_type(8))) short s16x8;

__device__ __forceinline__ unsigned bf16_rne_bits(float x) {
  unsigned u = __float_as_uint(x);
  return (u + 0x7fffu + ((u >> 16) & 1u)) >> 16;
}

__device__ __forceinline__ void gll16(const void* gsrc, void* ldst) {
  __builtin_amdgcn_global_load_lds(
      (const __attribute__((address_space(1))) unsigned char*)gsrc,
      (__attribute__((address_space(3))) unsigned char*)ldst, 16, 0, 0);
}

union BP2 { __hip_bfloat162 h; unsigned u; };
union BP8 { unsigned u[4]; s16x8 v; };

// ---------------- prep: tables only (zeroing moved into fused) -------------
__global__ void prep_kernel(const float* __restrict__ patch,
                            short* __restrict__ pa_swz,
                            short* __restrict__ p_T_perm) {
  int b = blockIdx.x, t = threadIdx.x;
  if (b < 64) {
    int u = b * 256 + t;                  // 16384 16B-units total
    int bt = u >> 11;
    int Lb = (u & 2047) * 16;
    int r  = Lb >> 9;
    int srcb = Lb ^ ((r & 15) << 4);      // involutive swizzle
    int p = bt * 64 + r;
    int d0 = (srcb & 511) >> 1;
    s16x8 v;
#pragma unroll
    for (int q = 0; q < 8; ++q)
      v[q] = (short)bf16_rne_bits(patch[(size_t)p * D_DIM + d0 + q]);
    *(s16x8*)(pa_swz + (size_t)u * 8) = v;
  } else {
    int u = (b - 64) * 256 + t;
    int g = u & 3, cc = (u >> 2) & 15, kc = (u >> 6) & 15, t2 = u >> 10;
    int d = t2 * 16 + cc;
    s16x8 v;
#pragma unroll
    for (int j = 0; j < 8; ++j) {
      int p = 32 * kc + 16 * (j >> 2) + 4 * g + (j & 3);
      v[j] = (short)bf16_rne_bits(patch[(size_t)p * D_DIM + d]);
    }
    *(s16x8*)(p_T_perm + (size_t)u * 8) = v;
  }
}

// LDS layout: SH[0..32767] = pa tiles (2 x 16KB), SH[32768..65535] = BT
// slab-sets (2 x 16KB). After the main loop the whole 64KB is reused as
// per-wave f32 transpose scratch (wave w: SH + w*16KB).
#define STAGE_PA(BUF, T) do {                                         \
  const char* gs_ = (const char*)pa_swz + (size_t)(T) * 16384         \
                    + (size_t)w * 4096 + (size_t)lane * 16;           \
  char* ls_ = SH + (BUF) * 16384 + w * 4096;                          \
  _Pragma("unroll")                                                   \
  for (int i_ = 0; i_ < 4; ++i_)                                      \
    gll16(gs_ + i_ * 1024, ls_ + i_ * 1024);                          \
} while (0)

#define STAGE_PT(BUF, T) do {                                         \
  const char* gs_ = (const char*)p_T_perm + ((size_t)(T) << 10)       \
                    + ((size_t)lane << 4);                            \
  _Pragma("unroll")                                                   \
  for (int i_ = 0; i_ < 4; ++i_) {                                    \
    int t2_ = i_ * 4 + w;                                             \
    gll16(gs_ + ((size_t)t2_ << 14),                                  \
          SH + 32768 + (BUF) * 16384 + (t2_ << 10) + (lane << 4));    \
  }                                                                   \
} while (0)

// finalize tile TT (values in pA0/pA1) + GEMM2 accumulate; all 16 A-slabs
// loaded upfront from LDS; MFMA cluster wrapped in setprio.
#define FIN_G2(TT) do {                                                        \
  const char* btp_ = SH + 32768 + ((TT) & 1) * 16384;                          \
  s16x8 aW[16];                                                                \
  _Pragma("unroll")                                                            \
  for (int q_ = 0; q_ < 16; ++q_)                                              \
    aW[q_] = *(const s16x8*)(btp_ + (q_ << 10) + (lidx << 4));                 \
  float e0=__expf(pA0[0]), e1=__expf(pA0[1]), e2=__expf(pA0[2]), e3=__expf(pA0[3]); \
  float e4=__expf(pA1[0]), e5=__expf(pA1[1]), e6=__expf(pA1[2]), e7=__expf(pA1[3]); \
  s += ((e0 + e1) + (e2 + e3)) + ((e4 + e5) + (e6 + e7));                      \
  int colb_ = 32 * (TT) + 4 * g;                                               \
  upd(pA0[0], colb_ + 0);  upd(pA0[1], colb_ + 1);                             \
  upd(pA0[2], colb_ + 2);  upd(pA0[3], colb_ + 3);                             \
  upd(pA1[0], colb_ + 16); upd(pA1[1], colb_ + 17);                            \
  upd(pA1[2], colb_ + 18); upd(pA1[3], colb_ + 19);                            \
  BP2 u0_, u1_, u2_, u3_;                                                      \
  u0_.h = __float22bfloat162_rn(make_float2(e0, e1));                          \
  u1_.h = __float22bfloat162_rn(make_float2(e2, e3));                          \
  u2_.h = __float22bfloat162_rn(make_float2(e4, e5));                          \
  u3_.h = __float22bfloat162_rn(make_float2(e6, e7));                          \
  BP8 pv_; pv_.u[0]=u0_.u; pv_.u[1]=u1_.u; pv_.u[2]=u2_.u; pv_.u[3]=u3_.u;     \
  s16x8 pf_ = pv_.v;                                                           \
  __builtin_amdgcn_s_setprio(1);                                               \
  _Pragma("unroll")                                                            \
  for (int q_ = 0; q_ < 16; ++q_)                                              \
    C2[q_] = __builtin_amdgcn_mfma_f32_16x16x32_bf16(aW[q_], pf_, C2[q_], 0, 0, 0); \
  __builtin_amdgcn_s_setprio(0);                                               \
} while (0)

// ---------------- fused: zeroing+logits+softmax+argmax+one-hot+recon+refine
__global__ __launch_bounds__(256, 2)
void fused_kernel(const float* __restrict__ node,
                  const float* __restrict__ patch,
                  const short* __restrict__ pa_swz,
                  const short* __restrict__ p_T_perm,
                  float* __restrict__ out_hot,
                  float* __restrict__ out_rec) {
  __shared__ __align__(16) char SH[65536];

  const int tid = threadIdx.x;
  const int lane = tid & 63;
  const int w = tid >> 6;
  const int cc = lane & 15, g = lane >> 4;
  const int G = blockIdx.x * 4 + w;             // 16-row group id
  const int myrow = G * 16 + cc;
  const bool ok = (G * 16) < N_ROWS;            // group-uniform

  STAGE_PA(0, 0);                               // tile-0 staging in flight

  // ---- zero this wave's 16 one-hot rows (NT stores; complete under loop) --
  if (ok) {
    const f32x4 z = (f32x4){0.f, 0.f, 0.f, 0.f};
    float* zb = out_hot + (size_t)(G * 16) * P_DIM;
#pragma unroll 1
    for (int rr = 0; rr < 16; ++rr) {
      __builtin_nontemporal_store(z, (f32x4*)(zb + rr * P_DIM + lane * 4));
      __builtin_nontemporal_store(z, (f32x4*)(zb + rr * P_DIM + 256 + lane * 4));
    }
  }

  // ---- node B-frags (hi only, nontemporal, cvt_pk pairs) ----
  s16x8 nhi[8];
  {
    const float* nr = node + (size_t)myrow * D_DIM;
#pragma unroll
    for (int kk = 0; kk < 8; ++kk) {
      f32x4 v0, v1;
      if (ok) {
        v0 = __builtin_nontemporal_load((const f32x4*)(nr + kk * 32 + g * 8));
        v1 = __builtin_nontemporal_load((const f32x4*)(nr + kk * 32 + g * 8 + 4));
      } else {
        v0 = (f32x4){0.f, 0.f, 0.f, 0.f};
        v1 = (f32x4){0.f, 0.f, 0.f, 0.f};
      }
      BP2 w0, w1, w2, w3;
      w0.h = __float22bfloat162_rn(make_float2(v0[0], v0[1]));
      w1.h = __float22bfloat162_rn(make_float2(v0[2], v0[3]));
      w2.h = __float22bfloat162_rn(make_float2(v1[0], v1[1]));
      w3.h = __float22bfloat162_rn(make_float2(v1[2], v1[3]));
      BP8 nv;
      nv.u[0] = w0.u; nv.u[1] = w1.u; nv.u[2] = w2.u; nv.u[3] = w3.u;
      nhi[kk] = nv.v;
    }
  }
  __syncthreads();                              // tile 0 staged

  f32x4 C2[16];
#pragma unroll
  for (int t2 = 0; t2 < 16; ++t2) C2[t2] = (f32x4){0.f, 0.f, 0.f, 0.f};
  float m1 = -1e30f, m2 = -1e30f, m3 = -1e30f;
  int i1 = 0, i2 = 0;
  float s = 0.f;
  f32x4 pA0 = (f32x4){0.f, 0.f, 0.f, 0.f};
  f32x4 pA1 = (f32x4){0.f, 0.f, 0.f, 0.f};

  const int lidx = (cc << 2) + g;

  auto upd = [&](float v, int col) {
    bool g1 = v > m1, g2 = v > m2, g3 = v > m3;
    m3 = g2 ? m2 : (g3 ? v : m3);
    i2 = g1 ? i1 : (g2 ? col : i2);
    m2 = g1 ? m1 : (g2 ? v : m2);
    i1 = g1 ? col : i1;
    m1 = g1 ? v : m1;
  };

#pragma unroll 1
  for (int t = 0; t < 16; ++t) {
    if (t < 15) STAGE_PA((t + 1) & 1, t + 1);
    STAGE_PT(t & 1, t);                         // used by FIN_G2(t) next iter
    // ---- GEMM1 tile t: even/odd split chains (4-deep dependencies) ----
    const char* bp = SH + (t & 1) * 16384;
    f32x4 a0e = (f32x4){0.f, 0.f, 0.f, 0.f};
    f32x4 a0o = (f32x4){0.f, 0.f, 0.f, 0.f};
    f32x4 a1e = (f32x4){0.f, 0.f, 0.f, 0.f};
    f32x4 a1o = (f32x4){0.f, 0.f, 0.f, 0.f};
    __builtin_amdgcn_s_setprio(1);
#pragma unroll
    for (int kk = 0; kk < 8; kk += 2) {
      int sw0 = ((kk << 6) | (g << 4)) ^ (cc << 4);
      int sw1 = (((kk + 1) << 6) | (g << 4)) ^ (cc << 4);
      s16x8 af00 = *(const s16x8*)(bp + (cc << 9) + sw0);
      s16x8 af10 = *(const s16x8*)(bp + ((16 + cc) << 9) + sw0);
      s16x8 af01 = *(const s16x8*)(bp + (cc << 9) + sw1);
      s16x8 af11 = *(const s16x8*)(bp + ((16 + cc) << 9) + sw1);
      a0e = __builtin_amdgcn_mfma_f32_16x16x32_bf16(af00, nhi[kk], a0e, 0, 0, 0);
      a1e = __builtin_amdgcn_mfma_f32_16x16x32_bf16(af10, nhi[kk], a1e, 0, 0, 0);
      a0o = __builtin_amdgcn_mfma_f32_16x16x32_bf16(af01, nhi[kk + 1], a0o, 0, 0, 0);
      a1o = __builtin_amdgcn_mfma_f32_16x16x32_bf16(af11, nhi[kk + 1], a1o, 0, 0, 0);
    }
    __builtin_amdgcn_s_setprio(0);
    // ---- finalize + GEMM2 for tile t-1 (A-slabs from BT[(t-1)&1]) ----
    if (t > 0) {
      FIN_G2(t - 1);
    }
    pA0 = a0e + a0o;
    pA1 = a1e + a1o;
    __syncthreads();   // staged writes (pa t+1, pT t) visible; reads done
  }
  // ---- epilogue: finalize + GEMM2 for tile 15 (BT[1] staged in iter 15) ----
  FIN_G2(15);

  // ---- merge top-3 across the 4 g-lanes of each row ----
#pragma unroll
  for (int mk = 16; mk <= 32; mk <<= 1) {
    float bm1 = __shfl_xor(m1, mk); int bi1 = __shfl_xor(i1, mk);
    float bm2 = __shfl_xor(m2, mk); int bi2 = __shfl_xor(i2, mk);
    float bm3 = __shfl_xor(m3, mk);
    bool sw = (bm1 > m1) || (bm1 == m1 && bi1 < i1);
    float am1 = sw ? bm1 : m1; int ai1 = sw ? bi1 : i1;
    float am2 = sw ? bm2 : m2; int ai2 = sw ? bi2 : i2;
    float am3 = sw ? bm3 : m3;
    float cm1 = sw ? m1 : bm1; int ci1 = sw ? i1 : bi1;
    float cm2 = sw ? m2 : bm2;
    bool t2b = (cm1 > am2) || (cm1 == am2 && ci1 < ai2);
    m1 = am1; i1 = ai1;
    m2 = t2b ? cm1 : am2; i2 = t2b ? ci1 : ai2;
    m3 = t2b ? fmaxf(am2, cm2) : fmaxf(am3, cm1);
  }
  s += __shfl_xor(s, 16);
  s += __shfl_xor(s, 32);
  const float inv = 1.0f / s;

  // ---- transposed rec store: C2 -> LDS scratch -> coalesced 1KB rows ----
  __syncthreads();                       // all FIN_G2(15) BT reads complete
  {
    float* scr = (float*)(SH + w * 16384);
#pragma unroll
    for (int t2 = 0; t2 < 16; ++t2) {
      int colb = 16 * t2 + 4 * g;
      f32x4 c2 = C2[t2];
      c2[0] *= inv; c2[1] *= inv; c2[2] *= inv; c2[3] *= inv;
      *(f32x4*)&scr[cc * 256 + (colb ^ ((cc & 3) << 4))] = c2;
    }
  }
  asm volatile("s_waitcnt lgkmcnt(0)" ::: "memory");   // wave-local RAW
  __builtin_amdgcn_sched_barrier(0);
  if (ok) {
    const float* scr = (const float*)(SH + w * 16384);
#pragma unroll 1
    for (int rr = 0; rr < 16; ++rr) {
      f32x4 v = *(const f32x4*)&scr[rr * 256 + ((lane * 4) ^ ((rr & 3) << 4))];
      __builtin_nontemporal_store(
          v, (f32x4*)(out_rec + (size_t)(G * 16 + rr) * D_DIM + lane * 4));
    }
  }

  // ---- one-hot 1.0 fixup (prologue zeros must be committed first) ----
  asm volatile("s_waitcnt vmcnt(0)" ::: "memory");     // zeros drained
  const bool flag12 = (m1 - m2 < TAU12);   // identical across the 4 g-lanes
  if (ok && g == 0 && !flag12)
    __builtin_nontemporal_store(1.0f, out_hot + (size_t)myrow * P_DIM + i1);

  // ---- in-wave refine: fp64 check of candidates for suspect rows ----
  unsigned long long smask = __ballot(ok && g == 0 && flag12);
  if (smask) {
    unsigned long long fmask = __ballot(ok && g == 0 && (m1 - m3 < TAU13));
#pragma unroll 1
    while (smask) {
      int src = __ffsll((long long)smask) - 1;
      smask &= smask - 1;
      int row = G * 16 + src;
      int ci1 = __shfl(i1, src);
      int ci2 = __shfl(i2, src);
      if (!((fmask >> src) & 1ull)) {
        // two-candidate exact fp64 dots; wave halves split the candidates
        int pidx = (lane >= 32) ? ci2 : ci1;
        int l5 = lane & 31;
        double sd = 0.0;
#pragma unroll
        for (int q = 0; q < 8; ++q) {
          int d = l5 * 8 + q;
          sd += (double)node[(size_t)row * D_DIM + d] *
                (double)patch[(size_t)pidx * D_DIM + d];
        }
#pragma unroll
        for (int mk = 1; mk <= 16; mk <<= 1) sd += __shfl_xor(sd, mk);
        double d1 = __shfl(sd, 0), d2 = __shfl(sd, 32);
        int win = (d2 > d1) ? ci2 : ((d2 == d1) ? (ci1 < ci2 ? ci1 : ci2) : ci1);
        if (lane == 0)
          out_hot[(size_t)row * P_DIM + win] = 1.0f;
      } else {
        // rare: full exact 512-way argmax (row is all zeros; write winner)
        double bv = -1e300;
        int bi = 0;
#pragma unroll 1
        for (int pp = 0; pp < 8; ++pp) {
          int p = pp * 64 + lane;
          double sd = 0.0;
          for (int d = 0; d < D_DIM; d += 4) {
            float4 f = *(const float4*)(patch + (size_t)p * D_DIM + d);
            sd += (double)node[(size_t)row * D_DIM + d]     * (double)f.x
                + (double)node[(size_t)row * D_DIM + d + 1] * (double)f.y
                + (double)node[(size_t)row * D_DIM + d + 2] * (double)f.z
                + (double)node[(size_t)row * D_DIM + d + 3] * (double)f.w;
          }
          if (sd > bv) { bv = sd; bi = p; }   // ascending p, strict >
        }
#pragma unroll
        for (int mk = 1; mk < 64; mk <<= 1) {
          double ov = __shfl_xor(bv, mk);
          int oi = __shfl_xor(bi, mk);
          if (ov > bv || (ov == bv && oi < bi)) { bv = ov; bi = oi; }
        }
        if (lane == 0)
          out_hot[(size_t)row * P_DIM + bi] = 1.0f;
      }
    }
  }
}

extern "C" void kernel_launch(void* const* d_in, const int* in_sizes, int n_in,
                              void* d_out, int out_size, void* d_ws, size_t ws_size,
                              hipStream_t stream) {
  const float* node  = (const float*)d_in[0];
  const float* patch = (const float*)d_in[1];
  float* out_hot = (float*)d_out;
  float* out_rec = out_hot + (size_t)N_ROWS * P_DIM;

  char* ws = (char*)d_ws;
  short* pa_swz   = (short*)ws;                                   // 256 KB
  short* p_T_perm = pa_swz + 131072;                              // 256 KB

  prep_kernel<<<128, 256, 0, stream>>>(patch, pa_swz, p_T_perm);
  fused_kernel<<<(N_ROWS + 63) / 64, 256, 0, stream>>>(node, patch, pa_swz,
                                                       p_T_perm, out_hot, out_rec);
}

// Round 21
// 223.624 us; speedup vs baseline: 1.1097x; 1.0577x over previous
//
#include <hip/hip_runtime.h>
#include <hip/hip_bf16.h>

#define N_ROWS 100000
#define P_DIM 512
#define D_DIM 256
#define TAU12 2.0e-2f
#define TAU13 1.5e-2f

typedef __attribute__((ext_vector_type(4))) float f32x4;
typedef __attribute__((ext_vector_type(8))) short s16x8;

__device__ __forceinline__ unsigned bf16_rne_bits(float x) {
  unsigned u = __float_as_uint(x);
  return (u + 0x7fffu + ((u >> 16) & 1u)) >> 16;
}

__device__ __forceinline__ void gll16(const void* gsrc, void* ldst) {
  __builtin_amdgcn_global_load_lds(
      (const __attribute__((address_space(1))) unsigned char*)gsrc,
      (__attribute__((address_space(3))) unsigned char*)ldst, 16, 0, 0);
}

union BP2 { __hip_bfloat162 h; unsigned u; };
union BP8 { unsigned u[4]; s16x8 v; };

// ---------------- prep: tables only ----------------
__global__ void prep_kernel(const float* __restrict__ patch,
                            short* __restrict__ pa_swz,
                            short* __restrict__ p_T_perm) {
  int b = blockIdx.x, t = threadIdx.x;
  if (b < 64) {
    int u = b * 256 + t;                  // 16384 16B-units total
    int bt = u >> 11;
    int Lb = (u & 2047) * 16;
    int r  = Lb >> 9;
    int srcb = Lb ^ ((r & 15) << 4);      // involutive swizzle
    int p = bt * 64 + r;
    int d0 = (srcb & 511) >> 1;
    s16x8 v;
#pragma unroll
    for (int q = 0; q < 8; ++q)
      v[q] = (short)bf16_rne_bits(patch[(size_t)p * D_DIM + d0 + q]);
    *(s16x8*)(pa_swz + (size_t)u * 8) = v;
  } else {
    int u = (b - 64) * 256 + t;
    int g = u & 3, cc = (u >> 2) & 15, kc = (u >> 6) & 15, t2 = u >> 10;
    int d = t2 * 16 + cc;
    s16x8 v;
#pragma unroll
    for (int j = 0; j < 8; ++j) {
      int p = 32 * kc + 16 * (j >> 2) + 4 * g + (j & 3);
      v[j] = (short)bf16_rne_bits(patch[(size_t)p * D_DIM + d]);
    }
    *(s16x8*)(p_T_perm + (size_t)u * 8) = v;
  }
}

// LDS layout: SH[0..32767] = pa tiles (2 x 16KB), SH[32768..65535] = BT
// slab-sets (2 x 16KB). After the main loop the whole 64KB is reused as
// per-wave f32 transpose scratch (wave w: SH + w*16KB).
#define STAGE_PA(BUF, T) do {                                         \
  const char* gs_ = (const char*)pa_swz + (size_t)(T) * 16384         \
                    + (size_t)w * 4096 + (size_t)lane * 16;           \
  char* ls_ = SH + (BUF) * 16384 + w * 4096;                          \
  _Pragma("unroll")                                                   \
  for (int i_ = 0; i_ < 4; ++i_)                                      \
    gll16(gs_ + i_ * 1024, ls_ + i_ * 1024);                          \
} while (0)

#define STAGE_PT(BUF, T) do {                                         \
  const char* gs_ = (const char*)p_T_perm + ((size_t)(T) << 10)       \
                    + ((size_t)lane << 4);                            \
  _Pragma("unroll")                                                   \
  for (int i_ = 0; i_ < 4; ++i_) {                                    \
    int t2_ = i_ * 4 + w;                                             \
    gll16(gs_ + ((size_t)t2_ << 14),                                  \
          SH + 32768 + (BUF) * 16384 + (t2_ << 10) + (lane << 4));    \
  }                                                                   \
} while (0)

// finalize tile TT (values in pA0/pA1) + GEMM2 accumulate; all 16 A-slabs
// loaded upfront from LDS; MFMA cluster wrapped in setprio.
#define FIN_G2(TT) do {                                                        \
  const char* btp_ = SH + 32768 + ((TT) & 1) * 16384;                          \
  s16x8 aW[16];                                                                \
  _Pragma("unroll")                                                            \
  for (int q_ = 0; q_ < 16; ++q_)                                              \
    aW[q_] = *(const s16x8*)(btp_ + (q_ << 10) + (lidx << 4));                 \
  float e0=__expf(pA0[0]), e1=__expf(pA0[1]), e2=__expf(pA0[2]), e3=__expf(pA0[3]); \
  float e4=__expf(pA1[0]), e5=__expf(pA1[1]), e6=__expf(pA1[2]), e7=__expf(pA1[3]); \
  s += ((e0 + e1) + (e2 + e3)) + ((e4 + e5) + (e6 + e7));                      \
  int colb_ = 32 * (TT) + 4 * g;                                               \
  upd(pA0[0], colb_ + 0);  upd(pA0[1], colb_ + 1);                             \
  upd(pA0[2], colb_ + 2);  upd(pA0[3], colb_ + 3);                             \
  upd(pA1[0], colb_ + 16); upd(pA1[1], colb_ + 17);                            \
  upd(pA1[2], colb_ + 18); upd(pA1[3], colb_ + 19);                            \
  BP2 u0_, u1_, u2_, u3_;                                                      \
  u0_.h = __float22bfloat162_rn(make_float2(e0, e1));                          \
  u1_.h = __float22bfloat162_rn(make_float2(e2, e3));                          \
  u2_.h = __float22bfloat162_rn(make_float2(e4, e5));                          \
  u3_.h = __float22bfloat162_rn(make_float2(e6, e7));                          \
  BP8 pv_; pv_.u[0]=u0_.u; pv_.u[1]=u1_.u; pv_.u[2]=u2_.u; pv_.u[3]=u3_.u;     \
  s16x8 pf_ = pv_.v;                                                           \
  __builtin_amdgcn_s_setprio(1);                                               \
  _Pragma("unroll")                                                            \
  for (int q_ = 0; q_ < 16; ++q_)                                              \
    C2[q_] = __builtin_amdgcn_mfma_f32_16x16x32_bf16(aW[q_], pf_, C2[q_], 0, 0, 0); \
  __builtin_amdgcn_s_setprio(0);                                               \
} while (0)

// ---------------- fused: zeroing+logits+softmax+argmax+one-hot+recon+refine
__global__ __launch_bounds__(256, 2)
void fused_kernel(const float* __restrict__ node,
                  const float* __restrict__ patch,
                  const short* __restrict__ pa_swz,
                  const short* __restrict__ p_T_perm,
                  float* __restrict__ out_hot,
                  float* __restrict__ out_rec) {
  __shared__ __align__(16) char SH[65536];

  const int tid = threadIdx.x;
  const int lane = tid & 63;
  const int w = tid >> 6;
  const int cc = lane & 15, g = lane >> 4;
  const int G = blockIdx.x * 4 + w;             // 16-row group id
  const int myrow = G * 16 + cc;
  const bool ok = (G * 16) < N_ROWS;            // group-uniform

  STAGE_PA(0, 0);                               // tile-0 staging in flight

  // ---- node B-frags FIRST (critical path for tile-0 MFMA) ----
  s16x8 nhi[8];
  {
    const float* nr = node + (size_t)myrow * D_DIM;
#pragma unroll
    for (int kk = 0; kk < 8; ++kk) {
      f32x4 v0, v1;
      if (ok) {
        v0 = __builtin_nontemporal_load((const f32x4*)(nr + kk * 32 + g * 8));
        v1 = __builtin_nontemporal_load((const f32x4*)(nr + kk * 32 + g * 8 + 4));
      } else {
        v0 = (f32x4){0.f, 0.f, 0.f, 0.f};
        v1 = (f32x4){0.f, 0.f, 0.f, 0.f};
      }
      BP2 w0, w1, w2, w3;
      w0.h = __float22bfloat162_rn(make_float2(v0[0], v0[1]));
      w1.h = __float22bfloat162_rn(make_float2(v0[2], v0[3]));
      w2.h = __float22bfloat162_rn(make_float2(v1[0], v1[1]));
      w3.h = __float22bfloat162_rn(make_float2(v1[2], v1[3]));
      BP8 nv;
      nv.u[0] = w0.u; nv.u[1] = w1.u; nv.u[2] = w2.u; nv.u[3] = w3.u;
      nhi[kk] = nv.v;
    }
  }
  __syncthreads();                              // tile 0 staged

  f32x4 C2[16];
#pragma unroll
  for (int t2 = 0; t2 < 16; ++t2) C2[t2] = (f32x4){0.f, 0.f, 0.f, 0.f};
  float m1 = -1e30f, m2 = -1e30f, m3 = -1e30f;
  int i1 = 0, i2 = 0;
  float s = 0.f;
  f32x4 pA0 = (f32x4){0.f, 0.f, 0.f, 0.f};
  f32x4 pA1 = (f32x4){0.f, 0.f, 0.f, 0.f};

  const int lidx = (cc << 2) + g;
  float* const zb = out_hot + (size_t)(G * 16) * P_DIM;
  const f32x4 zz = (f32x4){0.f, 0.f, 0.f, 0.f};

  auto upd = [&](float v, int col) {
    bool g1 = v > m1, g2 = v > m2, g3 = v > m3;
    m3 = g2 ? m2 : (g3 ? v : m3);
    i2 = g1 ? i1 : (g2 ? col : i2);
    m2 = g1 ? m1 : (g2 ? v : m2);
    i1 = g1 ? col : i1;
    m1 = g1 ? v : m1;
  };

#pragma unroll 1
  for (int t = 0; t < 16; ++t) {
    if (t < 15) STAGE_PA((t + 1) & 1, t + 1);
    STAGE_PT(t & 1, t);                         // used by FIN_G2(t) next iter
    // ---- GEMM1 tile t: even/odd split chains (4-deep dependencies) ----
    const char* bp = SH + (t & 1) * 16384;
    f32x4 a0e = (f32x4){0.f, 0.f, 0.f, 0.f};
    f32x4 a0o = (f32x4){0.f, 0.f, 0.f, 0.f};
    f32x4 a1e = (f32x4){0.f, 0.f, 0.f, 0.f};
    f32x4 a1o = (f32x4){0.f, 0.f, 0.f, 0.f};
    __builtin_amdgcn_s_setprio(1);
#pragma unroll
    for (int kk = 0; kk < 8; kk += 2) {
      int sw0 = ((kk << 6) | (g << 4)) ^ (cc << 4);
      int sw1 = (((kk + 1) << 6) | (g << 4)) ^ (cc << 4);
      s16x8 af00 = *(const s16x8*)(bp + (cc << 9) + sw0);
      s16x8 af10 = *(const s16x8*)(bp + ((16 + cc) << 9) + sw0);
      s16x8 af01 = *(const s16x8*)(bp + (cc << 9) + sw1);
      s16x8 af11 = *(const s16x8*)(bp + ((16 + cc) << 9) + sw1);
      a0e = __builtin_amdgcn_mfma_f32_16x16x32_bf16(af00, nhi[kk], a0e, 0, 0, 0);
      a1e = __builtin_amdgcn_mfma_f32_16x16x32_bf16(af10, nhi[kk], a1e, 0, 0, 0);
      a0o = __builtin_amdgcn_mfma_f32_16x16x32_bf16(af01, nhi[kk + 1], a0o, 0, 0, 0);
      a1o = __builtin_amdgcn_mfma_f32_16x16x32_bf16(af11, nhi[kk + 1], a1o, 0, 0, 0);
    }
    __builtin_amdgcn_s_setprio(0);
    // ---- zero one one-hot row per iteration (store queue idle here) ----
    if (ok) {
      __builtin_nontemporal_store(zz, (f32x4*)(zb + t * P_DIM + lane * 4));
      __builtin_nontemporal_store(zz, (f32x4*)(zb + t * P_DIM + 256 + lane * 4));
    }
    // ---- finalize + GEMM2 for tile t-1 (A-slabs from BT[(t-1)&1]) ----
    if (t > 0) {
      FIN_G2(t - 1);
    }
    pA0 = a0e + a0o;
    pA1 = a1e + a1o;
    __syncthreads();   // staged writes (pa t+1, pT t) visible; reads done
  }
  // ---- epilogue: finalize + GEMM2 for tile 15 (BT[1] staged in iter 15) ----
  FIN_G2(15);

  // ---- merge top-3 across the 4 g-lanes of each row ----
#pragma unroll
  for (int mk = 16; mk <= 32; mk <<= 1) {
    float bm1 = __shfl_xor(m1, mk); int bi1 = __shfl_xor(i1, mk);
    float bm2 = __shfl_xor(m2, mk); int bi2 = __shfl_xor(i2, mk);
    float bm3 = __shfl_xor(m3, mk);
    bool sw = (bm1 > m1) || (bm1 == m1 && bi1 < i1);
    float am1 = sw ? bm1 : m1; int ai1 = sw ? bi1 : i1;
    float am2 = sw ? bm2 : m2; int ai2 = sw ? bi2 : i2;
    float am3 = sw ? bm3 : m3;
    float cm1 = sw ? m1 : bm1; int ci1 = sw ? i1 : bi1;
    float cm2 = sw ? m2 : bm2;
    bool t2b = (cm1 > am2) || (cm1 == am2 && ci1 < ai2);
    m1 = am1; i1 = ai1;
    m2 = t2b ? cm1 : am2; i2 = t2b ? ci1 : ai2;
    m3 = t2b ? fmaxf(am2, cm2) : fmaxf(am3, cm1);
  }
  s += __shfl_xor(s, 16);
  s += __shfl_xor(s, 32);
  const float inv = 1.0f / s;

  // ---- transposed rec store: C2 -> LDS scratch -> coalesced 1KB rows ----
  __syncthreads();                       // all FIN_G2(15) BT reads complete
  {
    float* scr = (float*)(SH + w * 16384);
#pragma unroll
    for (int t2 = 0; t2 < 16; ++t2) {
      int colb = 16 * t2 + 4 * g;
      f32x4 c2 = C2[t2];
      c2[0] *= inv; c2[1] *= inv; c2[2] *= inv; c2[3] *= inv;
      *(f32x4*)&scr[cc * 256 + (colb ^ ((cc & 3) << 4))] = c2;
    }
  }
  asm volatile("s_waitcnt lgkmcnt(0)" ::: "memory");   // wave-local RAW
  __builtin_amdgcn_sched_barrier(0);
  if (ok) {
    const float* scr = (const float*)(SH + w * 16384);
#pragma unroll 1
    for (int rr = 0; rr < 16; ++rr) {
      f32x4 v = *(const f32x4*)&scr[rr * 256 + ((lane * 4) ^ ((rr & 3) << 4))];
      __builtin_nontemporal_store(
          v, (f32x4*)(out_rec + (size_t)(G * 16 + rr) * D_DIM + lane * 4));
    }
  }

  // ---- one-hot 1.0 fixup (loop zeros must be committed first) ----
  asm volatile("s_waitcnt vmcnt(0)" ::: "memory");     // zeros drained
  const bool flag12 = (m1 - m2 < TAU12);   // identical across the 4 g-lanes
  if (ok && g == 0 && !flag12)
    __builtin_nontemporal_store(1.0f, out_hot + (size_t)myrow * P_DIM + i1);

  // ---- in-wave refine: fp64 check of candidates for suspect rows ----
  unsigned long long smask = __ballot(ok && g == 0 && flag12);
  if (smask) {
    unsigned long long fmask = __ballot(ok && g == 0 && (m1 - m3 < TAU13));
#pragma unroll 1
    while (smask) {
      int src = __ffsll((long long)smask) - 1;
      smask &= smask - 1;
      int row = G * 16 + src;
      int ci1 = __shfl(i1, src);
      int ci2 = __shfl(i2, src);
      if (!((fmask >> src) & 1ull)) {
        // two-candidate exact fp64 dots; wave halves split the candidates
        int pidx = (lane >= 32) ? ci2 : ci1;
        int l5 = lane & 31;
        double sd = 0.0;
#pragma unroll
        for (int q = 0; q < 8; ++q) {
          int d = l5 * 8 + q;
          sd += (double)node[(size_t)row * D_DIM + d] *
                (double)patch[(size_t)pidx * D_DIM + d];
        }
#pragma unroll
        for (int mk = 1; mk <= 16; mk <<= 1) sd += __shfl_xor(sd, mk);
        double d1 = __shfl(sd, 0), d2 = __shfl(sd, 32);
        int win = (d2 > d1) ? ci2 : ((d2 == d1) ? (ci1 < ci2 ? ci1 : ci2) : ci1);
        if (lane == 0)
          out_hot[(size_t)row * P_DIM + win] = 1.0f;
      } else {
        // rare: full exact 512-way argmax (row is all zeros; write winner)
        double bv = -1e300;
        int bi = 0;
#pragma unroll 1
        for (int pp = 0; pp < 8; ++pp) {
          int p = pp * 64 + lane;
          double sd = 0.0;
          for (int d = 0; d < D_DIM; d += 4) {
            float4 f = *(const float4*)(patch + (size_t)p * D_DIM + d);
            sd += (double)node[(size_t)row * D_DIM + d]     * (double)f.x
                + (double)node[(size_t)row * D_DIM + d + 1] * (double)f.y
                + (double)node[(size_t)row * D_DIM + d + 2] * (double)f.z
                + (double)node[(size_t)row * D_DIM + d + 3] * (double)f.w;
          }
          if (sd > bv) { bv = sd; bi = p; }   // ascending p, strict >
        }
#pragma unroll
        for (int mk = 1; mk < 64; mk <<= 1) {
          double ov = __shfl_xor(bv, mk);
          int oi = __shfl_xor(bi, mk);
          if (ov > bv || (ov == bv && oi < bi)) { bv = ov; bi = oi; }
        }
        if (lane == 0)
          out_hot[(size_t)row * P_DIM + bi] = 1.0f;
      }
    }
  }
}

extern "C" void kernel_launch(void* const* d_in, const int* in_sizes, int n_in,
                              void* d_out, int out_size, void* d_ws, size_t ws_size,
                              hipStream_t stream) {
  const float* node  = (const float*)d_in[0];
  const float* patch = (const float*)d_in[1];
  float* out_hot = (float*)d_out;
  float* out_rec = out_hot + (size_t)N_ROWS * P_DIM;

  char* ws = (char*)d_ws;
  short* pa_swz   = (short*)ws;                                   // 256 KB
  short* p_T_perm = pa_swz + 131072;                              // 256 KB

  prep_kernel<<<128, 256, 0, stream>>>(patch, pa_swz, p_T_perm);
  fused_kernel<<<(N_ROWS + 63) / 64, 256, 0, stream>>>(node, patch, pa_swz,
                                                       p_T_perm, out_hot, out_rec);
}